// Round 3
// baseline (101.936 us; speedup 1.0000x reference)
//
#include <hip/hip_runtime.h>
#include <hip/hip_bf16.h>

using bf16x8 = __attribute__((ext_vector_type(8))) short;
using f32x4  = __attribute__((ext_vector_type(4))) float;

#define THREADS 256
#define NBLOCKS 2048
#define NTILES  31250   // 500000 / 16

__device__ __forceinline__ short f2bf(float f) {
    __hip_bfloat16 h = __float2bfloat16(f);
    return __builtin_bit_cast(short, h);
}

__device__ __forceinline__ bf16x8 cvt8(float4 a, float4 b) {
    bf16x8 r;
    r[0] = f2bf(a.x); r[1] = f2bf(a.y); r[2] = f2bf(a.z); r[3] = f2bf(a.w);
    r[4] = f2bf(b.x); r[5] = f2bf(b.y); r[6] = f2bf(b.z); r[7] = f2bf(b.w);
    return r;
}

__global__ __launch_bounds__(THREADS) void etl_kernel(
    const int*   __restrict__ bi,   // [500000,3]
    const float* __restrict__ t,    // [500000]
    const float* __restrict__ U,    // [300000,64]
    const float* __restrict__ W1,   // [193,50]
    const float* __restrict__ b1,   // [50]
    const float* __restrict__ W2,   // [50]
    const float* __restrict__ b2,   // [1]
    float*       __restrict__ out)  // [500000]
{
    // ---- build W1 bf16 B-fragments in LDS, fragment layout [nt*6+ks][lane][8]
    __shared__ short bsh[24][64][8];
    for (int e = threadIdx.x; e < 24 * 64; e += THREADS) {
        int f = e >> 6, l = e & 63;
        int nt = f / 6, ks = f - nt * 6;
        int n  = nt * 16 + (l & 15);
        int k0 = ks * 32 + ((l >> 4) << 3);
        bf16x8 v;
#pragma unroll
        for (int j = 0; j < 8; ++j) {
            float w = (n < 50) ? W1[(k0 + j) * 50 + n] : 0.f;
            v[j] = f2bf(w);
        }
        *(bf16x8*)(&bsh[f][l][0]) = v;
    }
    __syncthreads();

    const int lane = threadIdx.x & 63;
    const int g    = lane >> 4;    // 0..3
    const int ncol = lane & 15;    // n within N-tile / row within M-tile

    // hoist B fragments to registers (reused across all tiles of this wave)
    bf16x8 Bf[24];
#pragma unroll
    for (int f = 0; f < 24; ++f) Bf[f] = *(const bf16x8*)(&bsh[f][lane][0]);

    // epilogue invariants (exact fp32): t-row of W1, b1, W2 for this lane's 4 n's
    float w192[4], b1r[4], w2r[4];
#pragma unroll
    for (int nt = 0; nt < 4; ++nt) {
        int n = nt * 16 + ncol;
        bool vld = (n < 50);
        w192[nt] = vld ? W1[192 * 50 + n] : 0.f;
        b1r[nt]  = vld ? b1[n] : 0.f;
        w2r[nt]  = vld ? W2[n] : 0.f;
    }
    const float b2v = b2[0];

    const int nwaves = NBLOCKS * (THREADS / 64);
    const int wid    = blockIdx.x * (THREADS / 64) + (threadIdx.x >> 6);

    for (int tile = wid; tile < NTILES; tile += nwaves) {
        const int base = tile * 16;
        const int row  = base + ncol;   // this lane's A-row

        int i0 = bi[row * 3 + 0];
        int i1 = bi[row * 3 + 1] + 100000;
        int i2 = bi[row * 3 + 2] + 200000;

        // gather A fragments: lane (g,ncol) takes k = ks*32 + g*8 .. +7
        bf16x8 A[6];
        {
            const float* p0 = U + (size_t)i0 * 64 + g * 8;
            const float* p1 = U + (size_t)i1 * 64 + g * 8;
            const float* p2 = U + (size_t)i2 * 64 + g * 8;
            float4 a0 = ((const float4*)p0)[0], a1 = ((const float4*)p0)[1];
            float4 a2 = ((const float4*)(p0 + 32))[0], a3 = ((const float4*)(p0 + 32))[1];
            float4 b0 = ((const float4*)p1)[0], b1v4 = ((const float4*)p1)[1];
            float4 b2v4 = ((const float4*)(p1 + 32))[0], b3 = ((const float4*)(p1 + 32))[1];
            float4 c0 = ((const float4*)p2)[0], c1 = ((const float4*)p2)[1];
            float4 c2 = ((const float4*)(p2 + 32))[0], c3 = ((const float4*)(p2 + 32))[1];
            A[0] = cvt8(a0, a1);   A[1] = cvt8(a2, a3);
            A[2] = cvt8(b0, b1v4); A[3] = cvt8(b2v4, b3);
            A[4] = cvt8(c0, c1);   A[5] = cvt8(c2, c3);
        }

        f32x4 acc[4];
#pragma unroll
        for (int nt = 0; nt < 4; ++nt) acc[nt] = (f32x4){0.f, 0.f, 0.f, 0.f};

#pragma unroll
        for (int ks = 0; ks < 6; ++ks) {
#pragma unroll
            for (int nt = 0; nt < 4; ++nt) {
                acc[nt] = __builtin_amdgcn_mfma_f32_16x16x32_bf16(
                    A[ks], Bf[nt * 6 + ks], acc[nt], 0, 0, 0);
            }
        }

        // epilogue: D[m][n], m = g*4+r, n = nt*16+ncol
        float4 tv = *(const float4*)(t + base + g * 4);
        float tarr[4] = {tv.x, tv.y, tv.z, tv.w};
        float part[4] = {0.f, 0.f, 0.f, 0.f};
#pragma unroll
        for (int nt = 0; nt < 4; ++nt) {
#pragma unroll
            for (int r = 0; r < 4; ++r) {
                float pre = acc[nt][r] + tarr[r] * w192[nt] + b1r[nt];
                float e  = __expf(2.f * pre);
                float h  = 1.f - 2.f * __builtin_amdgcn_rcpf(e + 1.f);  // tanh
                part[r] += h * w2r[nt];
            }
        }
        // reduce across the 16 lanes of this g-group (lane bits 0..3)
#pragma unroll
        for (int r = 0; r < 4; ++r) {
#pragma unroll
            for (int m = 1; m < 16; m <<= 1)
                part[r] += __shfl_xor(part[r], m, 64);
        }
        if (ncol == 0) {
            float4 o = make_float4(part[0] + b2v, part[1] + b2v,
                                   part[2] + b2v, part[3] + b2v);
            *(float4*)(out + base + g * 4) = o;
        }
    }
}

extern "C" void kernel_launch(void* const* d_in, const int* in_sizes, int n_in,
                              void* d_out, int out_size, void* d_ws, size_t ws_size,
                              hipStream_t stream) {
    const int*   bi = (const int*)  d_in[0];
    const float* t  = (const float*)d_in[1];
    const float* U  = (const float*)d_in[2];
    const float* W1 = (const float*)d_in[3];
    const float* b1 = (const float*)d_in[4];
    const float* W2 = (const float*)d_in[5];
    const float* b2 = (const float*)d_in[6];
    float* out = (float*)d_out;
    etl_kernel<<<NBLOCKS, THREADS, 0, stream>>>(bi, t, U, W1, b1, W2, b2, out);
}

// Round 4
// 75.551 us; speedup vs baseline: 1.3492x; 1.3492x over previous
//
#include <hip/hip_runtime.h>
#include <hip/hip_bf16.h>

using bf16x8 = __attribute__((ext_vector_type(8))) short;
using f32x4  = __attribute__((ext_vector_type(4))) float;

#define THREADS 256
#define NBLOCKS 768
#define NTILES  31250   // 500000 / 16

__device__ __forceinline__ short f2bf(float f) {
    __hip_bfloat16 h = __float2bfloat16(f);
    return __builtin_bit_cast(short, h);
}

__device__ __forceinline__ bf16x8 cvt8(float4 a, float4 b) {
    bf16x8 r;
    r[0] = f2bf(a.x); r[1] = f2bf(a.y); r[2] = f2bf(a.z); r[3] = f2bf(a.w);
    r[4] = f2bf(b.x); r[5] = f2bf(b.y); r[6] = f2bf(b.z); r[7] = f2bf(b.w);
    return r;
}

__global__ __launch_bounds__(THREADS) void etl_kernel(
    const int*   __restrict__ bi,   // [500000,3]
    const float* __restrict__ t,    // [500000]
    const float* __restrict__ U,    // [300000,64]
    const float* __restrict__ W1,   // [193,50]
    const float* __restrict__ b1,   // [50]
    const float* __restrict__ W2,   // [50]
    const float* __restrict__ b2,   // [1]
    float*       __restrict__ out)  // [500000]
{
    // W1 bf16 B-fragments in LDS: [nt*6+ks][lane][8], 16B/lane contiguous
    __shared__ short bsh[24][64][8];
    for (int e = threadIdx.x; e < 24 * 64; e += THREADS) {
        int f = e >> 6, l = e & 63;
        int nt = f / 6, ks = f - nt * 6;
        int n  = nt * 16 + (l & 15);
        int k0 = ks * 32 + ((l >> 4) << 3);
        bf16x8 v;
#pragma unroll
        for (int j = 0; j < 8; ++j) {
            float w = (n < 50) ? W1[(k0 + j) * 50 + n] : 0.f;
            v[j] = f2bf(w);
        }
        *(bf16x8*)(&bsh[f][l][0]) = v;
    }
    __syncthreads();

    const int lane = threadIdx.x & 63;
    const int g    = lane >> 4;    // 0..3  (k-group)
    const int ncol = lane & 15;    // n within N-tile / row within M-tile

    // epilogue invariants (exact fp32)
    float w192[4], b1r[4], w2r[4];
#pragma unroll
    for (int nt = 0; nt < 4; ++nt) {
        int n = nt * 16 + ncol;
        bool vld = (n < 50);
        w192[nt] = vld ? W1[192 * 50 + n] : 0.f;
        b1r[nt]  = vld ? b1[n] : 0.f;
        w2r[nt]  = vld ? W2[n] : 0.f;
    }
    const float b2v = b2[0];

    const int nwaves = NBLOCKS * (THREADS / 64);
    int tile = blockIdx.x * (THREADS / 64) + (threadIdx.x >> 6);

    // ---------- pipeline prologue: tile's data, tile+nw's indices ----------
    int row = tile * 16 + ncol;
    int i0 = bi[row * 3 + 0];
    int i1 = bi[row * 3 + 1] + 100000;
    int i2 = bi[row * 3 + 2] + 200000;

    bf16x8 A[6];
    {
        const float* p0 = U + (size_t)i0 * 64 + g * 8;
        const float* p1 = U + (size_t)i1 * 64 + g * 8;
        const float* p2 = U + (size_t)i2 * 64 + g * 8;
        float4 a0 = ((const float4*)p0)[0],        a1 = ((const float4*)p0)[1];
        float4 a2 = ((const float4*)(p0 + 32))[0], a3 = ((const float4*)(p0 + 32))[1];
        float4 b0 = ((const float4*)p1)[0],        b1v4 = ((const float4*)p1)[1];
        float4 b2v4 = ((const float4*)(p1 + 32))[0], b3 = ((const float4*)(p1 + 32))[1];
        float4 c0 = ((const float4*)p2)[0],        c1 = ((const float4*)p2)[1];
        float4 c2 = ((const float4*)(p2 + 32))[0], c3 = ((const float4*)(p2 + 32))[1];
        A[0] = cvt8(a0, a1);   A[1] = cvt8(a2, a3);
        A[2] = cvt8(b0, b1v4); A[3] = cvt8(b2v4, b3);
        A[4] = cvt8(c0, c1);   A[5] = cvt8(c2, c3);
    }

    int nxt = tile + nwaves;
    bool has = nxt < NTILES;
    int j0 = 0, j1 = 0, j2 = 0;
    if (has) {
        int r2 = nxt * 16 + ncol;
        j0 = bi[r2 * 3 + 0];
        j1 = bi[r2 * 3 + 1] + 100000;
        j2 = bi[r2 * 3 + 2] + 200000;
    }

    // ---------- steady state ----------
    for (;;) {
        // 1) issue next tile's gathers (raw f32, no wait yet)
        float4 raw[12];
        if (has) {
            const float* p0 = U + (size_t)j0 * 64 + g * 8;
            const float* p1 = U + (size_t)j1 * 64 + g * 8;
            const float* p2 = U + (size_t)j2 * 64 + g * 8;
            raw[0]  = ((const float4*)p0)[0];        raw[1]  = ((const float4*)p0)[1];
            raw[2]  = ((const float4*)(p0 + 32))[0]; raw[3]  = ((const float4*)(p0 + 32))[1];
            raw[4]  = ((const float4*)p1)[0];        raw[5]  = ((const float4*)p1)[1];
            raw[6]  = ((const float4*)(p1 + 32))[0]; raw[7]  = ((const float4*)(p1 + 32))[1];
            raw[8]  = ((const float4*)p2)[0];        raw[9]  = ((const float4*)p2)[1];
            raw[10] = ((const float4*)(p2 + 32))[0]; raw[11] = ((const float4*)(p2 + 32))[1];
        }
        // 2) prefetch indices two tiles ahead
        int n2 = nxt + nwaves;
        bool has2 = has && (n2 < NTILES);
        int k0 = 0, k1 = 0, k2 = 0;
        if (has2) {
            int r3 = n2 * 16 + ncol;
            k0 = bi[r3 * 3 + 0];
            k1 = bi[r3 * 3 + 1] + 100000;
            k2 = bi[r3 * 3 + 2] + 200000;
        }

        // 3) compute current tile (B-frags re-read from LDS each tile;
        //    opaque lane defeats hoisting them into AGPRs across the loop)
        int lx = lane;
        asm volatile("" : "+v"(lx));
        f32x4 acc[4];
#pragma unroll
        for (int nt = 0; nt < 4; ++nt) acc[nt] = (f32x4){0.f, 0.f, 0.f, 0.f};
#pragma unroll
        for (int ks = 0; ks < 6; ++ks) {
#pragma unroll
            for (int nt = 0; nt < 4; ++nt) {
                bf16x8 Bf = *(const bf16x8*)(&bsh[nt * 6 + ks][lx][0]);
                acc[nt] = __builtin_amdgcn_mfma_f32_16x16x32_bf16(
                    A[ks], Bf, acc[nt], 0, 0, 0);
            }
        }

        const int base = tile * 16;
        float4 tv = *(const float4*)(t + base + g * 4);
        float tarr[4] = {tv.x, tv.y, tv.z, tv.w};
        float part[4] = {0.f, 0.f, 0.f, 0.f};
#pragma unroll
        for (int nt = 0; nt < 4; ++nt) {
#pragma unroll
            for (int r = 0; r < 4; ++r) {
                float pre = acc[nt][r] + tarr[r] * w192[nt] + b1r[nt];
                float e  = __expf(2.f * pre);
                float h  = 1.f - 2.f * __builtin_amdgcn_rcpf(e + 1.f);  // tanh
                part[r] += h * w2r[nt];
            }
        }
#pragma unroll
        for (int r = 0; r < 4; ++r) {
#pragma unroll
            for (int m = 1; m < 16; m <<= 1)
                part[r] += __shfl_xor(part[r], m, 64);
        }
        if (ncol == 0) {
            float4 o = make_float4(part[0] + b2v, part[1] + b2v,
                                   part[2] + b2v, part[3] + b2v);
            *(float4*)(out + base + g * 4) = o;
        }

        if (!has) break;

        // 4) rotate pipeline: cvt landed raw data -> A, shift indices
        A[0] = cvt8(raw[0], raw[1]);   A[1] = cvt8(raw[2], raw[3]);
        A[2] = cvt8(raw[4], raw[5]);   A[3] = cvt8(raw[6], raw[7]);
        A[4] = cvt8(raw[8], raw[9]);   A[5] = cvt8(raw[10], raw[11]);
        tile = nxt; nxt = n2; has = has2;
        j0 = k0; j1 = k1; j2 = k2;
    }
}

extern "C" void kernel_launch(void* const* d_in, const int* in_sizes, int n_in,
                              void* d_out, int out_size, void* d_ws, size_t ws_size,
                              hipStream_t stream) {
    const int*   bi = (const int*)  d_in[0];
    const float* t  = (const float*)d_in[1];
    const float* U  = (const float*)d_in[2];
    const float* W1 = (const float*)d_in[3];
    const float* b1 = (const float*)d_in[4];
    const float* W2 = (const float*)d_in[5];
    const float* b2 = (const float*)d_in[6];
    float* out = (float*)d_out;
    etl_kernel<<<NBLOCKS, THREADS, 0, stream>>>(bi, t, U, W1, b1, W2, b2, out);
}

// Round 5
// 74.284 us; speedup vs baseline: 1.3723x; 1.0171x over previous
//
#include <hip/hip_runtime.h>
#include <hip/hip_bf16.h>

using bf16x8 = __attribute__((ext_vector_type(8))) short;
using f32x4  = __attribute__((ext_vector_type(4))) float;

#define THREADS 256
#define NBLOCKS 768
#define NWAVES  (NBLOCKS * (THREADS / 64))   // 3072
#define NTILES  31250                        // 500000 / 16
#define NITER   11                           // ceil(NTILES / NWAVES)

__device__ __forceinline__ short f2bf(float f) {
    __hip_bfloat16 h = __float2bfloat16(f);
    return __builtin_bit_cast(short, h);
}

__device__ __forceinline__ bf16x8 cvt8(float4 a, float4 b) {
    bf16x8 r;
    r[0] = f2bf(a.x); r[1] = f2bf(a.y); r[2] = f2bf(a.z); r[3] = f2bf(a.w);
    r[4] = f2bf(b.x); r[5] = f2bf(b.y); r[6] = f2bf(b.z); r[7] = f2bf(b.w);
    return r;
}

__global__ __launch_bounds__(THREADS) void etl_kernel(
    const int*   __restrict__ bi,   // [500000,3]
    const float* __restrict__ t,    // [500000]
    const float* __restrict__ U,    // [300000,64]
    const float* __restrict__ W1,   // [193,50]
    const float* __restrict__ b1,   // [50]
    const float* __restrict__ W2,   // [50]
    const float* __restrict__ b2,   // [1]
    float*       __restrict__ out)  // [500000]
{
    // W1 bf16 B-fragments in LDS: [nt*6+ks][lane][8], 16B/lane contiguous
    __shared__ short bsh[24][64][8];
    for (int e = threadIdx.x; e < 24 * 64; e += THREADS) {
        int f = e >> 6, l = e & 63;
        int nt = f / 6, ks = f - nt * 6;
        int n  = nt * 16 + (l & 15);
        int k0 = ks * 32 + ((l >> 4) << 3);
        bf16x8 v;
#pragma unroll
        for (int j = 0; j < 8; ++j) {
            float w = (n < 50) ? W1[(k0 + j) * 50 + n] : 0.f;
            v[j] = f2bf(w);
        }
        *(bf16x8*)(&bsh[f][l][0]) = v;
    }
    __syncthreads();

    const int lane = threadIdx.x & 63;
    const int g    = lane >> 4;    // 0..3  (k-group / m-subrow group)
    const int ncol = lane & 15;    // n within N-tile / row within M-tile

    // epilogue invariants (exact fp32)
    float w192[4], b1r[4], w2r[4];
#pragma unroll
    for (int nt = 0; nt < 4; ++nt) {
        int n = nt * 16 + ncol;
        bool vld = (n < 50);
        w192[nt] = vld ? W1[192 * 50 + n] : 0.f;
        b1r[nt]  = vld ? b1[n] : 0.f;
        w2r[nt]  = vld ? W2[n] : 0.f;
    }
    const float b2v = b2[0];

    const int wid = blockIdx.x * (THREADS / 64) + (threadIdx.x >> 6);

    // clamped tile id for stage s (uniform per wave; tail tiles recompute
    // tile NTILES-1 with store masked off)
    auto tileAt = [&](int i) {
        int tl = wid + i * NWAVES;
        return tl < NTILES ? tl : NTILES - 1;
    };

#define GATHER12(dst, a0, a1, a2)                                              \
    {                                                                          \
        const float* p0 = U + (size_t)(a0) * 64 + g * 8;                       \
        const float* p1 = U + (size_t)(a1) * 64 + g * 8;                       \
        const float* p2 = U + (size_t)(a2) * 64 + g * 8;                       \
        dst[0]  = ((const float4*)p0)[0];        dst[1]  = ((const float4*)p0)[1];        \
        dst[2]  = ((const float4*)(p0 + 32))[0]; dst[3]  = ((const float4*)(p0 + 32))[1]; \
        dst[4]  = ((const float4*)p1)[0];        dst[5]  = ((const float4*)p1)[1];        \
        dst[6]  = ((const float4*)(p1 + 32))[0]; dst[7]  = ((const float4*)(p1 + 32))[1]; \
        dst[8]  = ((const float4*)p2)[0];        dst[9]  = ((const float4*)p2)[1];        \
        dst[10] = ((const float4*)(p2 + 32))[0]; dst[11] = ((const float4*)(p2 + 32))[1]; \
    }

    // ---------------- pipeline prologue ----------------
    bf16x8 A[6];
    float4 tcur, tN;
    float4 raw[12];
    int jn0, jn1, jn2;

    {   // tile(0): serial load + cvt
        int r0 = tileAt(0) * 16 + ncol;
        int i0 = bi[r0 * 3 + 0];
        int i1 = bi[r0 * 3 + 1] + 100000;
        int i2 = bi[r0 * 3 + 2] + 200000;
        float4 w[12];
        GATHER12(w, i0, i1, i2);
        A[0] = cvt8(w[0], w[1]);   A[1] = cvt8(w[2], w[3]);
        A[2] = cvt8(w[4], w[5]);   A[3] = cvt8(w[6], w[7]);
        A[4] = cvt8(w[8], w[9]);   A[5] = cvt8(w[10], w[11]);
        tcur = *(const float4*)(t + tileAt(0) * 16 + g * 4);
    }
    {   // tile(1): issue gathers (stay in flight)
        int r1 = tileAt(1) * 16 + ncol;
        int i0 = bi[r1 * 3 + 0];
        int i1 = bi[r1 * 3 + 1] + 100000;
        int i2 = bi[r1 * 3 + 2] + 200000;
        GATHER12(raw, i0, i1, i2);
        tN = *(const float4*)(t + tileAt(1) * 16 + g * 4);
    }
    {   // tile(2): issue index loads
        int r2 = tileAt(2) * 16 + ncol;
        jn0 = bi[r2 * 3 + 0];
        jn1 = bi[r2 * 3 + 1] + 100000;
        jn2 = bi[r2 * 3 + 2] + 200000;
    }

    // ---------------- steady state ----------------
    for (int i = 0; i < NITER; ++i) {
        const int  tl    = wid + i * NWAVES;
        const bool valid = tl < NTILES;
        const int  tile  = valid ? tl : NTILES - 1;
        const int  base  = tile * 16;

        // 1) compute tile(i) — consumes only A and tcur (both long resident)
        int lx = lane;
        asm volatile("" : "+v"(lx));
        f32x4 acc[4];
#pragma unroll
        for (int nt = 0; nt < 4; ++nt) acc[nt] = (f32x4){0.f, 0.f, 0.f, 0.f};
#pragma unroll
        for (int ks = 0; ks < 6; ++ks) {
#pragma unroll
            for (int nt = 0; nt < 4; ++nt) {
                bf16x8 Bf = *(const bf16x8*)(&bsh[nt * 6 + ks][lx][0]);
                acc[nt] = __builtin_amdgcn_mfma_f32_16x16x32_bf16(
                    A[ks], Bf, acc[nt], 0, 0, 0);
            }
        }

        float tarr[4] = {tcur.x, tcur.y, tcur.z, tcur.w};
        float part[4] = {0.f, 0.f, 0.f, 0.f};
#pragma unroll
        for (int nt = 0; nt < 4; ++nt) {
#pragma unroll
            for (int r = 0; r < 4; ++r) {
                float pre = acc[nt][r] + tarr[r] * w192[nt] + b1r[nt];
                float e  = __expf(2.f * pre);
                float h  = 1.f - 2.f * __builtin_amdgcn_rcpf(e + 1.f);  // tanh
                part[r] += h * w2r[nt];
            }
        }
#pragma unroll
        for (int r = 0; r < 4; ++r) {
#pragma unroll
            for (int m = 1; m < 16; m <<= 1)
                part[r] += __shfl_xor(part[r], m, 64);
        }
        if (valid && ncol == 0) {
            float4 o = make_float4(part[0] + b2v, part[1] + b2v,
                                   part[2] + b2v, part[3] + b2v);
            *(float4*)(out + base + g * 4) = o;
        }

        // 2) rotate: raw (tile i+1, issued one full body ago) -> A
        A[0] = cvt8(raw[0], raw[1]);   A[1] = cvt8(raw[2], raw[3]);
        A[2] = cvt8(raw[4], raw[5]);   A[3] = cvt8(raw[6], raw[7]);
        A[4] = cvt8(raw[8], raw[9]);   A[5] = cvt8(raw[10], raw[11]);
        tcur = tN;

        // 3) issue gathers for tile(i+2) — indices arrived (issued last body)
        GATHER12(raw, jn0, jn1, jn2);

        // 4) issue t for tile(i+2)
        tN = *(const float4*)(t + tileAt(i + 2) * 16 + g * 4);

        // 5) issue indices for tile(i+3)
        {
            int r3 = tileAt(i + 3) * 16 + ncol;
            jn0 = bi[r3 * 3 + 0];
            jn1 = bi[r3 * 3 + 1] + 100000;
            jn2 = bi[r3 * 3 + 2] + 200000;
        }
    }
#undef GATHER12
}

extern "C" void kernel_launch(void* const* d_in, const int* in_sizes, int n_in,
                              void* d_out, int out_size, void* d_ws, size_t ws_size,
                              hipStream_t stream) {
    const int*   bi = (const int*)  d_in[0];
    const float* t  = (const float*)d_in[1];
    const float* U  = (const float*)d_in[2];
    const float* W1 = (const float*)d_in[3];
    const float* b1 = (const float*)d_in[4];
    const float* W2 = (const float*)d_in[5];
    const float* b2 = (const float*)d_in[6];
    float* out = (float*)d_out;
    etl_kernel<<<NBLOCKS, THREADS, 0, stream>>>(bi, t, U, W1, b1, W2, b2, out);
}

// Round 6
// 62.775 us; speedup vs baseline: 1.6238x; 1.1833x over previous
//
#include <hip/hip_runtime.h>
#include <hip/hip_bf16.h>

using bf16x8 = __attribute__((ext_vector_type(8))) short;
using f32x4  = __attribute__((ext_vector_type(4))) float;

#define THREADS 256
#define NBLOCKS 768
#define NTILES  31250        // 500000 / 16
#define UELEMS  19200000     // 300000 * 64
#define WS_NEED (UELEMS * 2) // bf16 copy of U

__device__ __forceinline__ short f2bf(float f) {
    __hip_bfloat16 h = __float2bfloat16(f);
    return __builtin_bit_cast(short, h);
}

__device__ __forceinline__ bf16x8 cvt8(float4 a, float4 b) {
    bf16x8 r;
    r[0] = f2bf(a.x); r[1] = f2bf(a.y); r[2] = f2bf(a.z); r[3] = f2bf(a.w);
    r[4] = f2bf(b.x); r[5] = f2bf(b.y); r[6] = f2bf(b.z); r[7] = f2bf(b.w);
    return r;
}

// ---------- streaming f32 -> bf16 conversion of U into d_ws ----------
__global__ __launch_bounds__(256) void cvtU_kernel(const float* __restrict__ U,
                                                   short* __restrict__ Ub) {
    const int stride = gridDim.x * blockDim.x;
    for (int i = blockIdx.x * blockDim.x + threadIdx.x; i < UELEMS / 8; i += stride) {
        float4 a = ((const float4*)U)[2 * i];
        float4 b = ((const float4*)U)[2 * i + 1];
        ((bf16x8*)Ub)[i] = cvt8(a, b);
    }
}

// ---------- shared epilogue+MFMA body (templated on gather source) ----------
template <bool BF16PATH>
__global__ __launch_bounds__(THREADS) void etl_kernel(
    const int*   __restrict__ bi,   // [500000,3]
    const float* __restrict__ t,    // [500000]
    const float* __restrict__ U,    // [300000,64] f32
    const short* __restrict__ Ub,   // [300000,64] bf16 (d_ws) — used if BF16PATH
    const float* __restrict__ W1,   // [193,50]
    const float* __restrict__ b1,   // [50]
    const float* __restrict__ W2,   // [50]
    const float* __restrict__ b2,   // [1]
    float*       __restrict__ out)  // [500000]
{
    // W1 bf16 B-fragments via LDS -> hoisted to registers
    __shared__ short bsh[24][64][8];
    for (int e = threadIdx.x; e < 24 * 64; e += THREADS) {
        int f = e >> 6, l = e & 63;
        int nt = f / 6, ks = f - nt * 6;
        int n  = nt * 16 + (l & 15);
        int k0 = ks * 32 + ((l >> 4) << 3);
        bf16x8 v;
#pragma unroll
        for (int j = 0; j < 8; ++j) {
            float w = (n < 50) ? W1[(k0 + j) * 50 + n] : 0.f;
            v[j] = f2bf(w);
        }
        *(bf16x8*)(&bsh[f][l][0]) = v;
    }
    __syncthreads();

    const int lane = threadIdx.x & 63;
    const int g    = lane >> 4;    // 0..3 (k-chunk)
    const int ncol = lane & 15;    // A-row within tile / n within N-tile

    bf16x8 Bf[24];
#pragma unroll
    for (int f = 0; f < 24; ++f) Bf[f] = *(const bf16x8*)(&bsh[f][lane][0]);

    float w192[4], b1r[4], w2r[4];
#pragma unroll
    for (int nt = 0; nt < 4; ++nt) {
        int n = nt * 16 + ncol;
        bool vld = (n < 50);
        w192[nt] = vld ? W1[192 * 50 + n] : 0.f;
        b1r[nt]  = vld ? b1[n] : 0.f;
        w2r[nt]  = vld ? W2[n] : 0.f;
    }
    const float b2v = b2[0];

    const int nwaves = NBLOCKS * (THREADS / 64);
    const int wid    = blockIdx.x * (THREADS / 64) + (threadIdx.x >> 6);

    for (int tile = wid; tile < NTILES; tile += nwaves) {
        const int base = tile * 16;
        const int row  = base + ncol;

        int i0 = bi[row * 3 + 0];
        int i1 = bi[row * 3 + 1] + 100000;
        int i2 = bi[row * 3 + 2] + 200000;

        bf16x8 A[6];
        if constexpr (BF16PATH) {
            // bf16 gather: 6 x dwordx4, the load IS the fragment
            const short* q0 = Ub + (size_t)i0 * 64 + g * 8;
            const short* q1 = Ub + (size_t)i1 * 64 + g * 8;
            const short* q2 = Ub + (size_t)i2 * 64 + g * 8;
            A[0] = *(const bf16x8*)q0;  A[1] = *(const bf16x8*)(q0 + 32);
            A[2] = *(const bf16x8*)q1;  A[3] = *(const bf16x8*)(q1 + 32);
            A[4] = *(const bf16x8*)q2;  A[5] = *(const bf16x8*)(q2 + 32);
        } else {
            const float* p0 = U + (size_t)i0 * 64 + g * 8;
            const float* p1 = U + (size_t)i1 * 64 + g * 8;
            const float* p2 = U + (size_t)i2 * 64 + g * 8;
            float4 a0 = ((const float4*)p0)[0],        a1 = ((const float4*)p0)[1];
            float4 a2 = ((const float4*)(p0 + 32))[0], a3 = ((const float4*)(p0 + 32))[1];
            float4 b0 = ((const float4*)p1)[0],        b1v4 = ((const float4*)p1)[1];
            float4 b2v4 = ((const float4*)(p1 + 32))[0], b3 = ((const float4*)(p1 + 32))[1];
            float4 c0 = ((const float4*)p2)[0],        c1 = ((const float4*)p2)[1];
            float4 c2 = ((const float4*)(p2 + 32))[0], c3 = ((const float4*)(p2 + 32))[1];
            A[0] = cvt8(a0, a1);   A[1] = cvt8(a2, a3);
            A[2] = cvt8(b0, b1v4); A[3] = cvt8(b2v4, b3);
            A[4] = cvt8(c0, c1);   A[5] = cvt8(c2, c3);
        }

        f32x4 acc[4];
#pragma unroll
        for (int nt = 0; nt < 4; ++nt) acc[nt] = (f32x4){0.f, 0.f, 0.f, 0.f};
#pragma unroll
        for (int ks = 0; ks < 6; ++ks) {
#pragma unroll
            for (int nt = 0; nt < 4; ++nt) {
                acc[nt] = __builtin_amdgcn_mfma_f32_16x16x32_bf16(
                    A[ks], Bf[nt * 6 + ks], acc[nt], 0, 0, 0);
            }
        }

        float4 tv = *(const float4*)(t + base + g * 4);
        float tarr[4] = {tv.x, tv.y, tv.z, tv.w};
        float part[4] = {0.f, 0.f, 0.f, 0.f};
#pragma unroll
        for (int nt = 0; nt < 4; ++nt) {
#pragma unroll
            for (int r = 0; r < 4; ++r) {
                float pre = acc[nt][r] + tarr[r] * w192[nt] + b1r[nt];
                float e  = __expf(2.f * pre);
                float h  = 1.f - 2.f * __builtin_amdgcn_rcpf(e + 1.f);  // tanh
                part[r] += h * w2r[nt];
            }
        }
#pragma unroll
        for (int r = 0; r < 4; ++r) {
#pragma unroll
            for (int m = 1; m < 16; m <<= 1)
                part[r] += __shfl_xor(part[r], m, 64);
        }
        if (ncol == 0) {
            float4 o = make_float4(part[0] + b2v, part[1] + b2v,
                                   part[2] + b2v, part[3] + b2v);
            *(float4*)(out + base + g * 4) = o;
        }
    }
}

extern "C" void kernel_launch(void* const* d_in, const int* in_sizes, int n_in,
                              void* d_out, int out_size, void* d_ws, size_t ws_size,
                              hipStream_t stream) {
    const int*   bi = (const int*)  d_in[0];
    const float* t  = (const float*)d_in[1];
    const float* U  = (const float*)d_in[2];
    const float* W1 = (const float*)d_in[3];
    const float* b1 = (const float*)d_in[4];
    const float* W2 = (const float*)d_in[5];
    const float* b2 = (const float*)d_in[6];
    float* out = (float*)d_out;

    if (ws_size >= (size_t)WS_NEED) {
        short* Ub = (short*)d_ws;
        cvtU_kernel<<<2048, 256, 0, stream>>>(U, Ub);
        etl_kernel<true><<<NBLOCKS, THREADS, 0, stream>>>(
            bi, t, U, Ub, W1, b1, W2, b2, out);
    } else {
        etl_kernel<false><<<NBLOCKS, THREADS, 0, stream>>>(
            bi, t, U, (const short*)nullptr, W1, b1, W2, b2, out);
    }
}